// Round 14
// baseline (1168.780 us; speedup 1.0000x reference)
//
#include <hip/hip_runtime.h>
#include <math.h>

#define BB 32
#define TT 2048
#define HH 128

typedef float f32x2 __attribute__((ext_vector_type(2)));

// LDS-only barrier: waits LDS ops (lgkmcnt), leaves global loads/stores in
// flight across the barrier.
#define LDS_BARRIER() asm volatile("s_waitcnt lgkmcnt(0)\n\ts_barrier" ::: "memory")

// DPP helper: any DPP ctrl (quad_perm 0x00-0xFF, row_ror 0x120+n, ...).
#define QPERM_F(v, CTRL)                                                      \
  __int_as_float(__builtin_amdgcn_update_dpp(                                 \
      0, __float_as_int(v), (CTRL), 0xF, 0xF, true))

// ds_swizzle pattern must be a literal constant at the builtin call site.
template <int OFFS>
__device__ __forceinline__ float swz_xor(float v) {
  return __int_as_float(__builtin_amdgcn_ds_swizzle(__float_as_int(v), OFFS));
}

// Merging butterfly stage: lanes with bit=0 end with x summed over the lane
// pair; lanes with bit=1 end with y summed. (proven v6/R6-R13)
#define MERGE_DPP(x, y, bit, CTRL)                                            \
  ({                                                                          \
    float _k = (bit) ? (y) : (x);                                             \
    float _s = (bit) ? (x) : (y);                                             \
    _k + QPERM_F(_s, CTRL);                                                   \
  })
#define MERGE_SWZ(x, y, bit, OFFS)                                            \
  ({                                                                          \
    float _k = (bit) ? (y) : (x);                                             \
    float _s = (bit) ? (x) : (y);                                             \
    _k + swz_xor<OFFS>(_s);                                                   \
  })

// Packed dual FMA: acc.lo += w.lo * h[SEL]; acc.hi += w.hi * h[SEL].
// VOP3P op_sel broadcasts the chosen 32-bit half of src1 (h) to BOTH lanes:
//   SEL=0: op_sel:[0,0,0] op_sel_hi:[1,0,1]  (lo half of h to both)
//   SEL=1: op_sel:[0,1,0] op_sel_hi:[1,1,1]  (hi half of h to both)
// This halves FMA instruction count (96 -> 48/step) with zero dup-movs; the
// h pairs are free sub-extractions of the ds_read_b128 results.
template <int SEL>
__device__ __forceinline__ void pkfma(f32x2& acc, f32x2 w, f32x2 h) {
  if constexpr (SEL)
    asm("v_pk_fma_f32 %0, %1, %2, %0 op_sel:[0,1,0] op_sel_hi:[1,1,1]"
        : "+v"(acc)
        : "v"(w), "v"(h));
  else
    asm("v_pk_fma_f32 %0, %1, %2, %0 op_sel:[0,0,0] op_sel_hi:[1,0,1]"
        : "+v"(acc)
        : "v"(w), "v"(h));
}

__device__ __forceinline__ float tanh_fast(float s) {
  float ax = fabsf(s);
  float e = __expf(-2.0f * ax);
  float th = (1.0f - e) * __builtin_amdgcn_rcpf(1.0f + e);
  return copysignf(th, s);
}

// ---------------------------------------------------------------------------
// proj kernel v2 (unchanged from R13): out[r,:] = emb[tokens[r]] @ Wx0 + b0.
// ---------------------------------------------------------------------------
template <bool GATHER>
__global__ __launch_bounds__(256) void proj_kernel(
    const float* __restrict__ src, const int* __restrict__ tokens,
    const float* __restrict__ W, const float* __restrict__ bias,
    float* __restrict__ out) {
  const int tid = threadIdx.x;
  const int jj = tid & 31;
  const int rr = tid >> 5;
  const int base = blockIdx.x * 64;

  __shared__ __align__(16) float srow[64][HH];
  __shared__ int stok[64];

  if (GATHER) {
    if (tid < 64) stok[tid] = tokens[base + tid];
    __syncthreads();
  }

#pragma unroll
  for (int i = 0; i < 8; ++i) {
    int idx = tid + i * 256;
    int row = idx >> 5;
    int c4 = idx & 31;
    const float* s = GATHER ? (src + (size_t)stok[row] * HH)
                            : (src + (size_t)(base + row) * HH);
    *(float4*)&srow[row][c4 * 4] = *(const float4*)&s[c4 * 4];
  }
  __syncthreads();

  float4 b4 = *(const float4*)&bias[jj * 4];
  float4 acc[8];
#pragma unroll
  for (int i = 0; i < 8; ++i) acc[i] = b4;

  const float4* srow4 = (const float4*)&srow[0][0];  // [64][32]

  float4 w0 = *(const float4*)&W[0 * HH + jj * 4];
  float4 w1 = *(const float4*)&W[1 * HH + jj * 4];
  float4 w2 = *(const float4*)&W[2 * HH + jj * 4];
  float4 w3 = *(const float4*)&W[3 * HH + jj * 4];

  for (int k4 = 0; k4 < 32; ++k4) {
    int kn = (k4 + 1 < 32) ? 4 * (k4 + 1) : 0;
    float4 n0 = *(const float4*)&W[(kn + 0) * HH + jj * 4];
    float4 n1 = *(const float4*)&W[(kn + 1) * HH + jj * 4];
    float4 n2 = *(const float4*)&W[(kn + 2) * HH + jj * 4];
    float4 n3 = *(const float4*)&W[(kn + 3) * HH + jj * 4];

#pragma unroll
    for (int i = 0; i < 8; ++i) {
      float4 e = srow4[(rr * 8 + i) * 32 + k4];
      acc[i].x += e.x * w0.x + e.y * w1.x + e.z * w2.x + e.w * w3.x;
      acc[i].y += e.x * w0.y + e.y * w1.y + e.z * w2.y + e.w * w3.y;
      acc[i].z += e.x * w0.z + e.y * w1.z + e.z * w2.z + e.w * w3.z;
      acc[i].w += e.x * w0.w + e.y * w1.w + e.z * w2.w + e.w * w3.w;
    }
    w0 = n0;
    w1 = n1;
    w2 = n2;
    w3 = n3;
  }

#pragma unroll
  for (int i = 0; i < 8; ++i) {
    int row = base + rr * 8 + i;
    *(float4*)&out[(size_t)row * HH + jj * 4] = acc[i];
  }
}

// ---------------------------------------------------------------------------
// fused rnn kernel v14 = v13 + explicit v_pk_fma_f32 (op_sel h-broadcast).
//
// R13 counters: VALUBusy ~90% on active CUs -> issue-bound; 1246 cy/step ~=
// 1124 cy issue = ~281 inst/wave/step (96 FMA + ~96 accvgpr reads for the
// AGPR-spilled weights + overhead). The AGPR-read tax is structural (R4-R12
// closed remat/pin/waves_per_eu/AGPR-direct/in-loop-reload). The FMA count
// itself halves via VOP3P v_pk_fma_f32: 48 pk insts, h broadcast by op_sel
// straight from ds_read_b128 sub-pairs. Accumulation order per column is
// unchanged (kk = 0..7 sequential) -> identical numerics.
// ---------------------------------------------------------------------------
__global__ __launch_bounds__(512)
__attribute__((amdgpu_waves_per_eu(2, 2))) void rnn_fused_kernel(
    const float* __restrict__ xp0, float* __restrict__ out,
    const float* __restrict__ Wh0, const float* __restrict__ Wx1,
    const float* __restrict__ Wh1, const float* __restrict__ bias1,
    const int* __restrict__ tokens) {
  const int b = blockIdx.x;
  const int tid = threadIdx.x;
  const int lane = tid & 63;
  const int lb0 = lane & 1;
  const int lb1 = (lane >> 1) & 1;
  const int lb2 = (lane >> 2) & 1;  // layer select after reduce
  const int lb3 = (lane >> 3) & 1;  // duplicate half
  const int p = lane & 15;          // k-split 0..15, k in [8p, 8p+8)
  const int jg = tid >> 4;          // col-group 0..31
  const int colbase = jg * 4;
  const int kbase = p * 8;
  const int mycol = colbase + 2 * lb1 + lb0;  // output col after reduce

  // weights as f32x2 col-pairs: [kk][cpair], 48 pairs = 96 floats.
  f32x2 w0p[8][2], wxp[8][2], whp[8][2];
#pragma unroll
  for (int kk = 0; kk < 8; ++kk) {
    int row = kbase + kk;
    float4 v0 = *(const float4*)&Wh0[row * HH + colbase];
    float4 v1 = *(const float4*)&Wx1[row * HH + colbase];
    float4 v2 = *(const float4*)&Wh1[row * HH + colbase];
    w0p[kk][0] = (f32x2){v0.x, v0.y};
    w0p[kk][1] = (f32x2){v0.z, v0.w};
    wxp[kk][0] = (f32x2){v1.x, v1.y};
    wxp[kk][1] = (f32x2){v1.z, v1.w};
    whp[kk][0] = (f32x2){v2.x, v2.y};
    whp[kk][1] = (f32x2){v2.z, v2.w};
  }
  const float biasv = bias1[mycol];

  // mask bitmask: lane l holds bits for t in [32l, 32l+32); replicated/wave.
  const int* tok = tokens + b * TT;
  unsigned bits = 0;
#pragma unroll
  for (int i = 0; i < 8; ++i) {
    int4 tk = *(const int4*)&tok[lane * 32 + i * 4];
    bits |= (unsigned)(tk.x != 0) << (i * 4 + 0);
    bits |= (unsigned)(tk.y != 0) << (i * 4 + 1);
    bits |= (unsigned)(tk.z != 0) << (i * 4 + 2);
    bits |= (unsigned)(tk.w != 0) << (i * 4 + 3);
  }

  // h[k] at float-offset (k>>4)*20 + (k&15)  (80 B chunk stride; proven v6)
  __shared__ __align__(16) float h0s[2][160];
  __shared__ __align__(16) float h1s[2][160];
  if (tid < 160) {
    h0s[0][tid] = 0.0f;  // h0[-1]
    h1s[0][tid] = 0.0f;  // h1[-2]
  }

  const float* xp = xp0 + (size_t)b * TT * HH + mycol;
  float* outp = out + (size_t)b * TT * HH + mycol;

  const int roff = (p >> 1) * 20 + (p & 1) * 8;        // my k-slice read offset
  const int wslot = (mycol >> 4) * 20 + (mycol & 15);  // my publish slot

  float h = 0.0f;  // carried state for my (layer, col)
  float xc = xp[0];
  float xn = xp[HH];
  LDS_BARRIER();

#define RNN_STEP(RD0, RD1, WR0, WR1, T, HASPREV)                              \
  {                                                                           \
    const float* hb0 = &(RD0)[roff];                                          \
    const float* hb1 = &(RD1)[roff];                                          \
    float4 hA0 = *(const float4*)&hb0[0];                                     \
    float4 hB0 = *(const float4*)&hb0[4];                                     \
    float4 hA1 = *(const float4*)&hb1[0];                                     \
    float4 hB1 = *(const float4*)&hb1[4];                                     \
    f32x2 qp[4] = {(f32x2){hA0.x, hA0.y}, (f32x2){hA0.z, hA0.w},              \
                   (f32x2){hB0.x, hB0.y}, (f32x2){hB0.z, hB0.w}};             \
    f32x2 gp[4] = {(f32x2){hA1.x, hA1.y}, (f32x2){hA1.z, hA1.w},              \
                   (f32x2){hB1.x, hB1.y}, (f32x2){hB1.z, hB1.w}};             \
    float x2 = 0.0f;                                                          \
    if ((T) + 2 < TT) x2 = xp[(size_t)((T) + 2) * HH];                        \
    f32x2 a0p0 = {0.f, 0.f}, a0p1 = {0.f, 0.f};                               \
    f32x2 a1p0 = {0.f, 0.f}, a1p1 = {0.f, 0.f};                               \
    _Pragma("unroll") for (int kp = 0; kp < 4; ++kp) {                        \
      pkfma<0>(a0p0, w0p[2 * kp][0], qp[kp]);                                 \
      pkfma<0>(a0p1, w0p[2 * kp][1], qp[kp]);                                 \
      pkfma<0>(a1p0, wxp[2 * kp][0], qp[kp]);                                 \
      pkfma<0>(a1p1, wxp[2 * kp][1], qp[kp]);                                 \
      pkfma<0>(a1p0, whp[2 * kp][0], gp[kp]);                                 \
      pkfma<0>(a1p1, whp[2 * kp][1], gp[kp]);                                 \
      pkfma<1>(a0p0, w0p[2 * kp + 1][0], qp[kp]);                             \
      pkfma<1>(a0p1, w0p[2 * kp + 1][1], qp[kp]);                             \
      pkfma<1>(a1p0, wxp[2 * kp + 1][0], qp[kp]);                             \
      pkfma<1>(a1p1, wxp[2 * kp + 1][1], qp[kp]);                             \
      pkfma<1>(a1p0, whp[2 * kp + 1][0], gp[kp]);                             \
      pkfma<1>(a1p1, whp[2 * kp + 1][1], gp[kp]);                             \
    }                                                                         \
    float m0 = MERGE_DPP(a0p0.x, a0p0.y, lb0, 0xB1);                          \
    float m1 = MERGE_DPP(a0p1.x, a0p1.y, lb0, 0xB1);                          \
    float m2 = MERGE_DPP(a1p0.x, a1p0.y, lb0, 0xB1);                          \
    float m3 = MERGE_DPP(a1p1.x, a1p1.y, lb0, 0xB1);                          \
    float n0 = MERGE_DPP(m0, m1, lb1, 0x4E);                                  \
    float n1 = MERGE_DPP(m2, m3, lb1, 0x4E);                                  \
    float r = MERGE_SWZ(n0, n1, lb2, 0x101F); /* layer (xor4) */              \
    r += QPERM_F(r, 0x128); /* xor8 == row_ror:8 within 16-group */           \
    float s = r + (lb2 ? biasv : xc);                                         \
    unsigned wd0 = (unsigned)__builtin_amdgcn_readlane((int)bits, (T) >> 5);  \
    int mk0 = (wd0 >> ((T)&31)) & 1;                                          \
    int mk1 = 0;                                                              \
    if (HASPREV) {                                                            \
      unsigned wd1 =                                                          \
          (unsigned)__builtin_amdgcn_readlane((int)bits, ((T)-1) >> 5);       \
      mk1 = (wd1 >> (((T)-1) & 31)) & 1;                                      \
    }                                                                         \
    int mm = lb2 ? mk1 : mk0;                                                 \
    float th = tanh_fast(s);                                                  \
    h = mm ? th : h;                                                          \
    if (!lb3) {                                                               \
      if (lb2) {                                                              \
        (WR1)[wslot] = h; /* publish h1[T-1] */                               \
        if (HASPREV) outp[(size_t)((T)-1) * HH] = h;                          \
      } else {                                                                \
        (WR0)[wslot] = h; /* publish h0[T] */                                 \
      }                                                                       \
    }                                                                         \
    LDS_BARRIER();                                                            \
    xc = xn;                                                                  \
    xn = x2;                                                                  \
  }

  // peel t=0 (no previous step) and t=1
  RNN_STEP(h0s[0], h1s[0], h0s[1], h1s[1], 0, 0)
  RNN_STEP(h0s[1], h1s[1], h0s[0], h1s[0], 1, 1)

  // main loop, unrolled x2 with static buffer pointers (t=2..2047)
  for (int t = 2; t < TT; t += 2) {
    RNN_STEP(h0s[0], h1s[0], h0s[1], h1s[1], t, 1)
    RNN_STEP(h0s[1], h1s[1], h0s[0], h1s[0], t + 1, 1)
  }
#undef RNN_STEP

  // tail superstep (t == TT): h1[TT-1] from h0[TT-1] and h1[TT-2]; last loop
  // step (t=2047, odd) read buf1 and wrote buf0 -> both live in buf 0.
  {
    const float* hb0 = &h0s[0][roff];
    const float* hb1 = &h1s[0][roff];
    float4 hA0 = *(const float4*)&hb0[0];
    float4 hB0 = *(const float4*)&hb0[4];
    float4 hA1 = *(const float4*)&hb1[0];
    float4 hB1 = *(const float4*)&hb1[4];
    f32x2 qp[4] = {(f32x2){hA0.x, hA0.y}, (f32x2){hA0.z, hA0.w},
                   (f32x2){hB0.x, hB0.y}, (f32x2){hB0.z, hB0.w}};
    f32x2 gp[4] = {(f32x2){hA1.x, hA1.y}, (f32x2){hA1.z, hA1.w},
                   (f32x2){hB1.x, hB1.y}, (f32x2){hB1.z, hB1.w}};

    f32x2 a1p0 = {0.f, 0.f}, a1p1 = {0.f, 0.f};
#pragma unroll
    for (int kp = 0; kp < 4; ++kp) {
      pkfma<0>(a1p0, wxp[2 * kp][0], qp[kp]);
      pkfma<0>(a1p1, wxp[2 * kp][1], qp[kp]);
      pkfma<0>(a1p0, whp[2 * kp][0], gp[kp]);
      pkfma<0>(a1p1, whp[2 * kp][1], gp[kp]);
      pkfma<1>(a1p0, wxp[2 * kp + 1][0], qp[kp]);
      pkfma<1>(a1p1, wxp[2 * kp + 1][1], qp[kp]);
      pkfma<1>(a1p0, whp[2 * kp + 1][0], gp[kp]);
      pkfma<1>(a1p1, whp[2 * kp + 1][1], gp[kp]);
    }

    float m2 = MERGE_DPP(a1p0.x, a1p0.y, lb0, 0xB1);
    float m3 = MERGE_DPP(a1p1.x, a1p1.y, lb0, 0xB1);
    float n1 = MERGE_DPP(m2, m3, lb1, 0x4E);
    float r = n1 + swz_xor<0x101F>(n1);  // plain folds: only L1 values exist
    r += QPERM_F(r, 0x128);
    float s = r + biasv;

    const int t1 = TT - 1;
    unsigned wd1 = (unsigned)__builtin_amdgcn_readlane((int)bits, t1 >> 5);
    int mk1 = (wd1 >> (t1 & 31)) & 1;
    if (lb2) {  // lanes whose carried h is the h1 state
      float th = tanh_fast(s);
      float hv = mk1 ? th : h;
      if (!lb3) outp[(size_t)t1 * HH] = hv;
    }
  }
}

extern "C" void kernel_launch(void* const* d_in, const int* in_sizes, int n_in,
                              void* d_out, int out_size, void* d_ws,
                              size_t ws_size, hipStream_t stream) {
  const int* tokens = (const int*)d_in[0];
  const float* emb = (const float*)d_in[1];
  const float* Wx0 = (const float*)d_in[2];
  const float* Wh0 = (const float*)d_in[3];
  const float* b0 = (const float*)d_in[4];
  const float* Wx1 = (const float*)d_in[5];
  const float* Wh1 = (const float*)d_in[6];
  const float* b1 = (const float*)d_in[7];
  float* out = (float*)d_out;
  float* ws = (float*)d_ws;  // 32 MB: xp0

  const int rows = BB * TT;           // 65536
  const int proj_blocks = rows / 64;  // 1024

  proj_kernel<true><<<proj_blocks, 256, 0, stream>>>(emb, tokens, Wx0, b0, ws);
  rnn_fused_kernel<<<BB, 512, 0, stream>>>(ws, out, Wh0, Wx1, Wh1, b1, tokens);
}

// Round 15
// 1162.710 us; speedup vs baseline: 1.0052x; 1.0052x over previous
//
#include <hip/hip_runtime.h>
#include <math.h>

#define BB 32
#define TT 2048
#define HH 128

typedef float f32x2 __attribute__((ext_vector_type(2)));

// LDS-only barrier: waits LDS ops (lgkmcnt), leaves global loads/stores in
// flight across the barrier.
#define LDS_BARRIER() asm volatile("s_waitcnt lgkmcnt(0)\n\ts_barrier" ::: "memory")

// DPP helper: any DPP ctrl (quad_perm 0x00-0xFF, row_ror 0x120+n, ...).
#define QPERM_F(v, CTRL)                                                      \
  __int_as_float(__builtin_amdgcn_update_dpp(                                 \
      0, __float_as_int(v), (CTRL), 0xF, 0xF, true))

// ds_swizzle pattern must be a literal constant at the builtin call site.
template <int OFFS>
__device__ __forceinline__ float swz_xor(float v) {
  return __int_as_float(__builtin_amdgcn_ds_swizzle(__float_as_int(v), OFFS));
}

// Merging butterfly stage: lanes with bit=0 end with x summed over the lane
// pair; lanes with bit=1 end with y summed. (proven v6/R6-R14)
#define MERGE_DPP(x, y, bit, CTRL)                                            \
  ({                                                                          \
    float _k = (bit) ? (y) : (x);                                             \
    float _s = (bit) ? (x) : (y);                                             \
    _k + QPERM_F(_s, CTRL);                                                   \
  })
#define MERGE_SWZ(x, y, bit, OFFS)                                            \
  ({                                                                          \
    float _k = (bit) ? (y) : (x);                                             \
    float _s = (bit) ? (x) : (y);                                             \
    _k + swz_xor<OFFS>(_s);                                                   \
  })

// Packed dual FMA with op_sel h-broadcast (proven R14: halves FMA inst count,
// identical numerics).
template <int SEL>
__device__ __forceinline__ void pkfma(f32x2& acc, f32x2 w, f32x2 h) {
  if constexpr (SEL)
    asm("v_pk_fma_f32 %0, %1, %2, %0 op_sel:[0,1,0] op_sel_hi:[1,1,1]"
        : "+v"(acc)
        : "v"(w), "v"(h));
  else
    asm("v_pk_fma_f32 %0, %1, %2, %0 op_sel:[0,0,0] op_sel_hi:[1,0,1]"
        : "+v"(acc)
        : "v"(w), "v"(h));
}

__device__ __forceinline__ float tanh_fast(float s) {
  float ax = fabsf(s);
  float e = __expf(-2.0f * ax);
  float th = (1.0f - e) * __builtin_amdgcn_rcpf(1.0f + e);
  return copysignf(th, s);
}

// ---------------------------------------------------------------------------
// proj kernel v2 (unchanged): out[r,:] = emb[tokens[r]] @ Wx0 + b0.
// ---------------------------------------------------------------------------
template <bool GATHER>
__global__ __launch_bounds__(256) void proj_kernel(
    const float* __restrict__ src, const int* __restrict__ tokens,
    const float* __restrict__ W, const float* __restrict__ bias,
    float* __restrict__ out) {
  const int tid = threadIdx.x;
  const int jj = tid & 31;
  const int rr = tid >> 5;
  const int base = blockIdx.x * 64;

  __shared__ __align__(16) float srow[64][HH];
  __shared__ int stok[64];

  if (GATHER) {
    if (tid < 64) stok[tid] = tokens[base + tid];
    __syncthreads();
  }

#pragma unroll
  for (int i = 0; i < 8; ++i) {
    int idx = tid + i * 256;
    int row = idx >> 5;
    int c4 = idx & 31;
    const float* s = GATHER ? (src + (size_t)stok[row] * HH)
                            : (src + (size_t)(base + row) * HH);
    *(float4*)&srow[row][c4 * 4] = *(const float4*)&s[c4 * 4];
  }
  __syncthreads();

  float4 b4 = *(const float4*)&bias[jj * 4];
  float4 acc[8];
#pragma unroll
  for (int i = 0; i < 8; ++i) acc[i] = b4;

  const float4* srow4 = (const float4*)&srow[0][0];  // [64][32]

  float4 w0 = *(const float4*)&W[0 * HH + jj * 4];
  float4 w1 = *(const float4*)&W[1 * HH + jj * 4];
  float4 w2 = *(const float4*)&W[2 * HH + jj * 4];
  float4 w3 = *(const float4*)&W[3 * HH + jj * 4];

  for (int k4 = 0; k4 < 32; ++k4) {
    int kn = (k4 + 1 < 32) ? 4 * (k4 + 1) : 0;
    float4 n0 = *(const float4*)&W[(kn + 0) * HH + jj * 4];
    float4 n1 = *(const float4*)&W[(kn + 1) * HH + jj * 4];
    float4 n2 = *(const float4*)&W[(kn + 2) * HH + jj * 4];
    float4 n3 = *(const float4*)&W[(kn + 3) * HH + jj * 4];

#pragma unroll
    for (int i = 0; i < 8; ++i) {
      float4 e = srow4[(rr * 8 + i) * 32 + k4];
      acc[i].x += e.x * w0.x + e.y * w1.x + e.z * w2.x + e.w * w3.x;
      acc[i].y += e.x * w0.y + e.y * w1.y + e.z * w2.y + e.w * w3.y;
      acc[i].z += e.x * w0.z + e.y * w1.z + e.z * w2.z + e.w * w3.z;
      acc[i].w += e.x * w0.w + e.y * w1.w + e.z * w2.w + e.w * w3.w;
    }
    w0 = n0;
    w1 = n1;
    w2 = n2;
    w3 = n3;
  }

#pragma unroll
  for (int i = 0; i < 8; ++i) {
    int row = base + rr * 8 + i;
    *(float4*)&out[(size_t)row * HH + jj * 4] = acc[i];
  }
}

// ---------------------------------------------------------------------------
// fused rnn kernel v15 = v14 + chunked mask words (SALU offload).
//
// R14 counters: VALUBusy fell 11.3->7.7% with time flat -> step = per-SIMD
// issue (~720cy) + ~500cy unhidden serial chain; FMA issue no longer the
// binding term. Remaining clean shave: the mask word readlane(bits, t>>5)
// changes only every 32 steps. Chunk the t-loop (64 x 32 steps): 1 readlane
// per chunk, per-step bit-extract becomes uniform SALU (s_bfe), ~3 VALU
// inst/step left vs ~10. If this lands neutral, the structure is at its
// measured floor: issue 720 + chain 500 ~= 1250cy/step x 2049 steps.
// ---------------------------------------------------------------------------
__global__ __launch_bounds__(512)
__attribute__((amdgpu_waves_per_eu(2, 2))) void rnn_fused_kernel(
    const float* __restrict__ xp0, float* __restrict__ out,
    const float* __restrict__ Wh0, const float* __restrict__ Wx1,
    const float* __restrict__ Wh1, const float* __restrict__ bias1,
    const int* __restrict__ tokens) {
  const int b = blockIdx.x;
  const int tid = threadIdx.x;
  const int lane = tid & 63;
  const int lb0 = lane & 1;
  const int lb1 = (lane >> 1) & 1;
  const int lb2 = (lane >> 2) & 1;  // layer select after reduce
  const int lb3 = (lane >> 3) & 1;  // duplicate half
  const int p = lane & 15;          // k-split 0..15, k in [8p, 8p+8)
  const int jg = tid >> 4;          // col-group 0..31
  const int colbase = jg * 4;
  const int kbase = p * 8;
  const int mycol = colbase + 2 * lb1 + lb0;  // output col after reduce

  // weights as f32x2 col-pairs: [kk][cpair], 48 pairs = 96 floats.
  f32x2 w0p[8][2], wxp[8][2], whp[8][2];
#pragma unroll
  for (int kk = 0; kk < 8; ++kk) {
    int row = kbase + kk;
    float4 v0 = *(const float4*)&Wh0[row * HH + colbase];
    float4 v1 = *(const float4*)&Wx1[row * HH + colbase];
    float4 v2 = *(const float4*)&Wh1[row * HH + colbase];
    w0p[kk][0] = (f32x2){v0.x, v0.y};
    w0p[kk][1] = (f32x2){v0.z, v0.w};
    wxp[kk][0] = (f32x2){v1.x, v1.y};
    wxp[kk][1] = (f32x2){v1.z, v1.w};
    whp[kk][0] = (f32x2){v2.x, v2.y};
    whp[kk][1] = (f32x2){v2.z, v2.w};
  }
  const float biasv = bias1[mycol];

  // mask bitmask: lane l holds bits for t in [32l, 32l+32); replicated/wave.
  const int* tok = tokens + b * TT;
  unsigned bits = 0;
#pragma unroll
  for (int i = 0; i < 8; ++i) {
    int4 tk = *(const int4*)&tok[lane * 32 + i * 4];
    bits |= (unsigned)(tk.x != 0) << (i * 4 + 0);
    bits |= (unsigned)(tk.y != 0) << (i * 4 + 1);
    bits |= (unsigned)(tk.z != 0) << (i * 4 + 2);
    bits |= (unsigned)(tk.w != 0) << (i * 4 + 3);
  }

  // h[k] at float-offset (k>>4)*20 + (k&15)  (80 B chunk stride; proven v6)
  __shared__ __align__(16) float h0s[2][160];
  __shared__ __align__(16) float h1s[2][160];
  if (tid < 160) {
    h0s[0][tid] = 0.0f;  // h0[-1]
    h1s[0][tid] = 0.0f;  // h1[-2]
  }

  const float* xp = xp0 + (size_t)b * TT * HH + mycol;
  float* outp = out + (size_t)b * TT * HH + mycol;

  const int roff = (p >> 1) * 20 + (p & 1) * 8;        // my k-slice read offset
  const int wslot = (mycol >> 4) * 20 + (mycol & 15);  // my publish slot

  float h = 0.0f;  // carried state for my (layer, col)
  float xc = xp[0];
  float xn = xp[HH];
  LDS_BARRIER();

// W0V/W1V are wave-uniform unsigned words (SGPR): mask word for step T and
// for step T-1. Extraction is SALU; only the lb2-select and h-update are VALU.
#define RNN_STEP(RD0, RD1, WR0, WR1, T, W0V, W1V, HASPREV)                    \
  {                                                                           \
    const float* hb0 = &(RD0)[roff];                                          \
    const float* hb1 = &(RD1)[roff];                                          \
    float4 hA0 = *(const float4*)&hb0[0];                                     \
    float4 hB0 = *(const float4*)&hb0[4];                                     \
    float4 hA1 = *(const float4*)&hb1[0];                                     \
    float4 hB1 = *(const float4*)&hb1[4];                                     \
    f32x2 qp[4] = {(f32x2){hA0.x, hA0.y}, (f32x2){hA0.z, hA0.w},              \
                   (f32x2){hB0.x, hB0.y}, (f32x2){hB0.z, hB0.w}};             \
    f32x2 gp[4] = {(f32x2){hA1.x, hA1.y}, (f32x2){hA1.z, hA1.w},              \
                   (f32x2){hB1.x, hB1.y}, (f32x2){hB1.z, hB1.w}};             \
    float x2 = 0.0f;                                                          \
    if ((T) + 2 < TT) x2 = xp[(size_t)((T) + 2) * HH];                        \
    f32x2 a0p0 = {0.f, 0.f}, a0p1 = {0.f, 0.f};                               \
    f32x2 a1p0 = {0.f, 0.f}, a1p1 = {0.f, 0.f};                               \
    _Pragma("unroll") for (int kp = 0; kp < 4; ++kp) {                        \
      pkfma<0>(a0p0, w0p[2 * kp][0], qp[kp]);                                 \
      pkfma<0>(a0p1, w0p[2 * kp][1], qp[kp]);                                 \
      pkfma<0>(a1p0, wxp[2 * kp][0], qp[kp]);                                 \
      pkfma<0>(a1p1, wxp[2 * kp][1], qp[kp]);                                 \
      pkfma<0>(a1p0, whp[2 * kp][0], gp[kp]);                                 \
      pkfma<0>(a1p1, whp[2 * kp][1], gp[kp]);                                 \
      pkfma<1>(a0p0, w0p[2 * kp + 1][0], qp[kp]);                             \
      pkfma<1>(a0p1, w0p[2 * kp + 1][1], qp[kp]);                             \
      pkfma<1>(a1p0, wxp[2 * kp + 1][0], qp[kp]);                             \
      pkfma<1>(a1p1, wxp[2 * kp + 1][1], qp[kp]);                             \
      pkfma<1>(a1p0, whp[2 * kp + 1][0], gp[kp]);                             \
      pkfma<1>(a1p1, whp[2 * kp + 1][1], gp[kp]);                             \
    }                                                                         \
    float m0 = MERGE_DPP(a0p0.x, a0p0.y, lb0, 0xB1);                          \
    float m1 = MERGE_DPP(a0p1.x, a0p1.y, lb0, 0xB1);                          \
    float m2 = MERGE_DPP(a1p0.x, a1p0.y, lb0, 0xB1);                          \
    float m3 = MERGE_DPP(a1p1.x, a1p1.y, lb0, 0xB1);                          \
    float n0 = MERGE_DPP(m0, m1, lb1, 0x4E);                                  \
    float n1 = MERGE_DPP(m2, m3, lb1, 0x4E);                                  \
    float r = MERGE_SWZ(n0, n1, lb2, 0x101F); /* layer (xor4) */              \
    r += QPERM_F(r, 0x128); /* xor8 == row_ror:8 within 16-group */           \
    float s = r + (lb2 ? biasv : xc);                                         \
    int mk0 = (int)(((W0V) >> ((T)&31)) & 1u);        /* SALU (uniform) */    \
    int mk1 = (HASPREV) ? (int)(((W1V) >> (((T)-1) & 31)) & 1u) : 0;          \
    int mm = lb2 ? mk1 : mk0;                                                 \
    float th = tanh_fast(s);                                                  \
    h = mm ? th : h;                                                          \
    if (!lb3) {                                                               \
      if (lb2) {                                                              \
        (WR1)[wslot] = h; /* publish h1[T-1] */                               \
        if (HASPREV) outp[(size_t)((T)-1) * HH] = h;                          \
      } else {                                                                \
        (WR0)[wslot] = h; /* publish h0[T] */                                 \
      }                                                                       \
    }                                                                         \
    LDS_BARRIER();                                                            \
    xc = xn;                                                                  \
    xn = x2;                                                                  \
  }

  unsigned wcur = (unsigned)__builtin_amdgcn_readlane((int)bits, 0);
  unsigned wprev = 0;

  // chunk 0 (t = 0..31): peel t=0 (no previous step) and t=1
  RNN_STEP(h0s[0], h1s[0], h0s[1], h1s[1], 0, wcur, 0u, 0)
  RNN_STEP(h0s[1], h1s[1], h0s[0], h1s[0], 1, wcur, wcur, 1)
  for (int t = 2; t < 32; t += 2) {
    RNN_STEP(h0s[0], h1s[0], h0s[1], h1s[1], t, wcur, wcur, 1)
    RNN_STEP(h0s[1], h1s[1], h0s[0], h1s[0], t + 1, wcur, wcur, 1)
  }

  // chunks 1..63: one readlane per chunk; first pair's t-1 uses wprev
  for (int c = 1; c < 64; ++c) {
    wprev = wcur;
    wcur = (unsigned)__builtin_amdgcn_readlane((int)bits, c);
    const int tb = 32 * c;
    RNN_STEP(h0s[0], h1s[0], h0s[1], h1s[1], tb, wcur, wprev, 1)
    RNN_STEP(h0s[1], h1s[1], h0s[0], h1s[0], tb + 1, wcur, wcur, 1)
    for (int t = tb + 2; t < tb + 32; t += 2) {
      RNN_STEP(h0s[0], h1s[0], h0s[1], h1s[1], t, wcur, wcur, 1)
      RNN_STEP(h0s[1], h1s[1], h0s[0], h1s[0], t + 1, wcur, wcur, 1)
    }
  }
#undef RNN_STEP

  // tail superstep (t == TT): h1[TT-1] from h0[TT-1] and h1[TT-2]; last loop
  // step (t=2047, odd) read buf1 and wrote buf0 -> both live in buf 0.
  {
    const float* hb0 = &h0s[0][roff];
    const float* hb1 = &h1s[0][roff];
    float4 hA0 = *(const float4*)&hb0[0];
    float4 hB0 = *(const float4*)&hb0[4];
    float4 hA1 = *(const float4*)&hb1[0];
    float4 hB1 = *(const float4*)&hb1[4];
    f32x2 qp[4] = {(f32x2){hA0.x, hA0.y}, (f32x2){hA0.z, hA0.w},
                   (f32x2){hB0.x, hB0.y}, (f32x2){hB0.z, hB0.w}};
    f32x2 gp[4] = {(f32x2){hA1.x, hA1.y}, (f32x2){hA1.z, hA1.w},
                   (f32x2){hB1.x, hB1.y}, (f32x2){hB1.z, hB1.w}};

    f32x2 a1p0 = {0.f, 0.f}, a1p1 = {0.f, 0.f};
#pragma unroll
    for (int kp = 0; kp < 4; ++kp) {
      pkfma<0>(a1p0, wxp[2 * kp][0], qp[kp]);
      pkfma<0>(a1p1, wxp[2 * kp][1], qp[kp]);
      pkfma<0>(a1p0, whp[2 * kp][0], gp[kp]);
      pkfma<0>(a1p1, whp[2 * kp][1], gp[kp]);
      pkfma<1>(a1p0, wxp[2 * kp + 1][0], qp[kp]);
      pkfma<1>(a1p1, wxp[2 * kp + 1][1], qp[kp]);
      pkfma<1>(a1p0, whp[2 * kp + 1][0], gp[kp]);
      pkfma<1>(a1p1, whp[2 * kp + 1][1], gp[kp]);
    }

    float m2 = MERGE_DPP(a1p0.x, a1p0.y, lb0, 0xB1);
    float m3 = MERGE_DPP(a1p1.x, a1p1.y, lb0, 0xB1);
    float n1 = MERGE_DPP(m2, m3, lb1, 0x4E);
    float r = n1 + swz_xor<0x101F>(n1);  // plain folds: only L1 values exist
    r += QPERM_F(r, 0x128);
    float s = r + biasv;

    const int t1 = TT - 1;
    int mk1 = (int)((wcur >> (t1 & 31)) & 1u);  // t1 = 2047, chunk 63 = wcur
    if (lb2) {  // lanes whose carried h is the h1 state
      float th = tanh_fast(s);
      float hv = mk1 ? th : h;
      if (!lb3) outp[(size_t)t1 * HH] = hv;
    }
  }
}

extern "C" void kernel_launch(void* const* d_in, const int* in_sizes, int n_in,
                              void* d_out, int out_size, void* d_ws,
                              size_t ws_size, hipStream_t stream) {
  const int* tokens = (const int*)d_in[0];
  const float* emb = (const float*)d_in[1];
  const float* Wx0 = (const float*)d_in[2];
  const float* Wh0 = (const float*)d_in[3];
  const float* b0 = (const float*)d_in[4];
  const float* Wx1 = (const float*)d_in[5];
  const float* Wh1 = (const float*)d_in[6];
  const float* b1 = (const float*)d_in[7];
  float* out = (float*)d_out;
  float* ws = (float*)d_ws;  // 32 MB: xp0

  const int rows = BB * TT;           // 65536
  const int proj_blocks = rows / 64;  // 1024

  proj_kernel<true><<<proj_blocks, 256, 0, stream>>>(emb, tokens, Wx0, b0, ws);
  rnn_fused_kernel<<<BB, 512, 0, stream>>>(ws, out, Wh0, Wx1, Wh1, b1, tokens);
}